// Round 7
// baseline (507.067 us; speedup 1.0000x reference)
//
#include <hip/hip_runtime.h>
#include <hip/hip_cooperative_groups.h>
#include <cmath>

namespace cg = cooperative_groups;

#define NH 16
#define NKV 4
#define HD 128
#define DMODEL 2048
#define BB 4
#define SQV 1024
#define SQA 64
#define SCACHE 256
#define STOT 1344   // SCACHE + SQV + SQA
#define SQTOT 1088  // SQV + SQA
#define NSPLIT 7    // attention K-partitions (192 keys = 3 chunks each)

typedef unsigned short u16;
typedef __attribute__((ext_vector_type(8))) short short8;
typedef __attribute__((ext_vector_type(4))) float f32x4;

__device__ __forceinline__ float b2f(u16 u) {
    union { float f; unsigned int i; } x; x.i = ((unsigned int)u) << 16; return x.f;
}
__device__ __forceinline__ u16 f2b(float f) {
    unsigned int x = __float_as_uint(f);
    x = x + 0x7fffu + ((x >> 16) & 1u);   // RNE
    return (u16)(x >> 16);
}

// async global->LDS, 16B per lane. LDS dest is wave-uniform base + lane*16 (linear).
__device__ __forceinline__ void gload16(const void* g, void* l) {
    __builtin_amdgcn_global_load_lds((const __attribute__((address_space(1))) void*)g,
                                     (__attribute__((address_space(3))) void*)l, 16, 0, 0);
}

struct MegaArgs {
    const float *mask, *kc, *vc, *hv, *ha;
    const float *w0; u16* o0;   // Wk_vlm -> WkvT
    const float *w1; u16* o1;   // Wv_vlm -> WvvT
    const float *w2; u16* o2;   // Wk_act -> WkaT
    const float *w3; u16* o3;   // Wv_act -> WvaT
    const float *w4; u16* o4;   // Wq_act -> WqaT
    const float *w5; u16* o5;   // Wo_act -> WoT
    const int *pos_vlm, *pos_act;
    float *cosT, *sinT;
    u16 *maskS, *K_all, *VT_all, *hv16, *ha16, *Qbuf, *po;
    float* pml;
    u16* AO;
    float* out;
};

// ---------------- transpose body: fp32 [2048][N] tile -> bf16 [N][2048] ---------------
__device__ __forceinline__ void transpose_body(u16* t, const float* in, u16* out, int N,
                                               int bx, int by) {
    int n0 = bx * 64, k0 = by * 64;
    int tid = threadIdx.x;
    int r = tid >> 3;
    int c8 = (tid & 7) * 8;
#pragma unroll
    for (int h = 0; h < 2; h++) {
        int k = r + h * 32;
        const float* f = in + (size_t)(k0 + k) * N + n0 + c8;
        float4 a = *(const float4*)f, b = *(const float4*)(f + 4);
        u16 vv[8] = {f2b(a.x), f2b(a.y), f2b(a.z), f2b(a.w),
                     f2b(b.x), f2b(b.y), f2b(b.z), f2b(b.w)};
#pragma unroll
        for (int j = 0; j < 8; j++) t[(c8 + j) * 66 + k] = vv[j];
    }
    __syncthreads();
#pragma unroll
    for (int h = 0; h < 2; h++) {
        int n = r + h * 32;
        short8 v;
#pragma unroll
        for (int j = 0; j < 8; j++) ((u16*)&v)[j] = t[n * 66 + c8 + j];
        *(short8*)(out + (size_t)(n0 + n) * 2048 + k0 + c8) = v;
    }
}

// ------------- v_cache transpose: fp32 [key 256][d 128] -> bf16 VT [d][STOT keys] -----
__device__ __forceinline__ void transpose_vc(u16* tv, const float* vc, u16* VT, int idx) {
    int bkv = idx >> 3, t8 = idx & 7;
    int key0 = (t8 >> 1) * 64, d0 = (t8 & 1) * 64;
    const float* in = vc + ((size_t)bkv * SCACHE + key0) * HD + d0;
    u16* out = VT + ((size_t)bkv * HD + d0) * STOT + key0;
    int tid = threadIdx.x;
    int r = tid >> 3, c8 = (tid & 7) * 8;
#pragma unroll
    for (int h = 0; h < 2; h++) {
        int k = r + h * 32;                     // key row
        const float* f = in + (size_t)k * HD + c8;
        float4 a = *(const float4*)f, b = *(const float4*)(f + 4);
        u16 vv[8] = {f2b(a.x), f2b(a.y), f2b(a.z), f2b(a.w),
                     f2b(b.x), f2b(b.y), f2b(b.z), f2b(b.w)};
#pragma unroll
        for (int j = 0; j < 8; j++) tv[(c8 + j) * 66 + k] = vv[j];
    }
    __syncthreads();
#pragma unroll
    for (int h = 0; h < 2; h++) {
        int d = r + h * 32;                     // d row of VT
        short8 v;
#pragma unroll
        for (int j = 0; j < 8; j++) ((u16*)&v)[j] = tv[d * 66 + c8 + j];
        *(short8*)(out + (size_t)d * STOT + c8) = v;
    }
}

// ---------------- prep work unit (one gx in [0,9488)) ---------------------------------
__device__ __forceinline__ void prep_work(const MegaArgs& a, u16* L, int gx) {
    int tid = threadIdx.x;
    if (gx < 3072) {
        if (gx < 256)        transpose_body(L, a.w0, a.o0, 512,  gx & 7,  gx >> 3);
        else if (gx < 512)   { int g = gx - 256;  transpose_body(L, a.w1, a.o1, 512,  g & 7,  g >> 3); }
        else if (gx < 768)   { int g = gx - 512;  transpose_body(L, a.w2, a.o2, 512,  g & 7,  g >> 3); }
        else if (gx < 1024)  { int g = gx - 768;  transpose_body(L, a.w3, a.o3, 512,  g & 7,  g >> 3); }
        else if (gx < 2048)  { int g = gx - 1024; transpose_body(L, a.w4, a.o4, 2048, g & 31, g >> 5); }
        else                 { int g = gx - 2048; transpose_body(L, a.w5, a.o5, 2048, g & 31, g >> 5); }
        return;
    }
    int bx = gx - 3072;
    if (bx < 336) {
        int i = bx * 256 + tid;
        if (i < STOT * 64) {
            int p = i >> 6, j = i & 63;
            float inv = __expf(-(float)j * (9.210340371976184f / 64.0f));
            float ang = (float)p * inv;
            a.cosT[i] = cosf(ang);
            a.sinT[i] = sinf(ang);
        }
    } else if (bx < 1680) {
        int i = (bx - 336) * 256 + tid;   // 344064 = 1344*256 exact
        int b = i / (SQA * STOT);
        int r = i % (SQA * STOT);
        size_t s = (size_t)b * SQTOT * STOT + (size_t)SQV * STOT + r;
        a.maskS[i] = f2b(a.mask[s]);
    } else if (bx < 1936) {
        int i = (bx - 1680) * 256 + tid;  // 65536 groups of 8 (K cache only)
        int e = i * 8;
        int bk = e / (SCACHE * HD);
        int off = e % (SCACHE * HD);
        size_t dst = (size_t)bk * STOT * HD + off;
        const float* fk = a.kc + e;
        u16 tk[8];
#pragma unroll
        for (int j = 0; j < 8; j++) tk[j] = f2b(fk[j]);
        *(short8*)(a.K_all + dst) = *(short8*)tk;
    } else if (bx < 6032) {
        int i = (bx - 1936) * 256 + tid;  // 1,048,576 groups of 8
        int e = i * 8;
        const float* f = a.hv + e;
        float4 p0 = *(const float4*)f, p1 = *(const float4*)(f + 4);
        u16 t8[8] = {f2b(p0.x), f2b(p0.y), f2b(p0.z), f2b(p0.w),
                     f2b(p1.x), f2b(p1.y), f2b(p1.z), f2b(p1.w)};
        *(short8*)(a.hv16 + e) = *(short8*)t8;
    } else if (bx < 6288) {
        int i = (bx - 6032) * 256 + tid;  // 65,536 groups of 8
        int e = i * 8;
        const float* f = a.ha + e;
        float4 p0 = *(const float4*)f, p1 = *(const float4*)(f + 4);
        u16 t8[8] = {f2b(p0.x), f2b(p0.y), f2b(p0.z), f2b(p0.w),
                     f2b(p1.x), f2b(p1.y), f2b(p1.z), f2b(p1.w)};
        *(short8*)(a.ha16 + e) = *(short8*)t8;
    } else {
        transpose_vc(L, a.vc, a.VT_all, bx - 6288);   // 128 works
    }
}

// ---------------- qkv tile (r3-proven 2-phase dbuf, BK=64, 64x128) --------------------
__device__ __forceinline__ void qkv_tile(const MegaArgs& a, u16* smem,
                                         const u16* A, const u16* Bt,
                                         int m0, int n0, int path, int head) {
    int tid = threadIdx.x;
    int w = tid >> 6, lane = tid & 63;
    int la = lane & 15, lg = lane >> 4;
    int wm = (w & 1) * 32;
    int c2 = w >> 1;
    int ntab[4] = {c2 * 2, c2 * 2 + 1, c2 * 2 + 4, c2 * 2 + 5};

    f32x4 acc[2][4];
#pragma unroll
    for (int i = 0; i < 2; i++)
#pragma unroll
        for (int j = 0; j < 4; j++) acc[i][j] = (f32x4){0.f, 0.f, 0.f, 0.f};

    int srow = tid >> 3;
    int scsrc = (((tid & 7) * 16) ^ ((srow & 7) << 4)) >> 1;   // swizzled src col (u16)

#define STAGE_QKV(CB, KB) do {                                                        \
        u16* Ab_ = smem + (CB) * 12288;                                               \
        u16* Bb_ = Ab_ + 4096;                                                        \
        _Pragma("unroll")                                                             \
        for (int h = 0; h < 2; h++)                                                   \
            gload16(A + (size_t)(m0 + srow + h * 32) * DMODEL + (KB) + scsrc,         \
                    Ab_ + h * 2048 + tid * 8);                                        \
        _Pragma("unroll")                                                             \
        for (int h = 0; h < 4; h++)                                                   \
            gload16(Bt + (size_t)(n0 + srow + h * 32) * DMODEL + (KB) + scsrc,        \
                    Bb_ + h * 2048 + tid * 8);                                        \
    } while (0)

    STAGE_QKV(0, 0);
    int cur = 0;
    int swr = (la & 7) << 3;
    for (int kb = 0; kb < DMODEL; kb += 64) {
        if (kb + 64 < DMODEL) {
            STAGE_QKV(cur ^ 1, kb + 64);
            asm volatile("s_waitcnt vmcnt(6)" ::: "memory");
        } else {
            asm volatile("s_waitcnt vmcnt(0)" ::: "memory");
        }
        __builtin_amdgcn_s_barrier();
        asm volatile("" ::: "memory");
        const u16* Ac = smem + cur * 12288;
        const u16* Bc = Ac + 4096;
#pragma unroll
        for (int kk = 0; kk < 2; kk++) {
            short8 af[2], bf[4];
            int cc = (kk * 32 + lg * 8) ^ swr;
#pragma unroll
            for (int mt = 0; mt < 2; mt++)
                af[mt] = *(const short8*)&Ac[(wm + mt * 16 + la) * 64 + cc];
#pragma unroll
            for (int nt = 0; nt < 4; nt++)
                bf[nt] = *(const short8*)&Bc[(ntab[nt] * 16 + la) * 64 + cc];
#pragma unroll
            for (int mt = 0; mt < 2; mt++)
#pragma unroll
                for (int nt = 0; nt < 4; nt++)
                    acc[mt][nt] = __builtin_amdgcn_mfma_f32_16x16x32_bf16(af[mt], bf[nt], acc[mt][nt], 0, 0, 0);
        }
        __builtin_amdgcn_s_barrier();
        cur ^= 1;
    }
#undef STAGE_QKV

#pragma unroll
    for (int mt = 0; mt < 2; mt++) {
#pragma unroll
        for (int r = 0; r < 4; r++) {
            int gm = m0 + wm + mt * 16 + lg * 4 + r;
            if (path <= 1) {                       // vlm K/V
                int b = gm >> 10, s = gm & 1023;
                if (path == 0) {
                    size_t base = ((size_t)(b * NKV + head) * STOT + SCACHE + s) * HD;
                    int pos = a.pos_vlm[gm];
#pragma unroll
                    for (int i = 0; i < 2; i++) {
                        int dlo = ntab[i] * 16 + la;  // in [0,64)
                        float x1 = acc[mt][i][r], x2 = acc[mt][i + 2][r];
                        float cs = a.cosT[pos * 64 + dlo], sn = a.sinT[pos * 64 + dlo];
                        a.K_all[base + dlo]      = f2b(x1 * cs - x2 * sn);
                        a.K_all[base + dlo + 64] = f2b(x2 * cs + x1 * sn);
                    }
                } else {
                    size_t vt = ((size_t)(b * NKV + head) * HD) * STOT + SCACHE + s;
#pragma unroll
                    for (int i = 0; i < 4; i++) {
                        int d = ntab[i] * 16 + la;    // in [0,128)
                        a.VT_all[vt + (size_t)d * STOT] = f2b(acc[mt][i][r]);
                    }
                }
            } else {                               // action Q/K/V
                int b = gm >> 6, s = gm & 63;
                if (path == 2) {
                    int pos = a.pos_act[gm];
                    size_t qb = ((size_t)(b * NH + head) * SQA + s) * HD;
#pragma unroll
                    for (int i = 0; i < 2; i++) {
                        int dlo = ntab[i] * 16 + la;
                        float x1 = acc[mt][i][r], x2 = acc[mt][i + 2][r];
                        float cs = a.cosT[pos * 64 + dlo], sn = a.sinT[pos * 64 + dlo];
                        a.Qbuf[qb + dlo]      = f2b(x1 * cs - x2 * sn);
                        a.Qbuf[qb + dlo + 64] = f2b(x2 * cs + x1 * sn);
                    }
                } else if (path == 3) {
                    int pos = a.pos_act[gm];
                    size_t base = ((size_t)(b * NKV + head) * STOT + SCACHE + SQV + s) * HD;
#pragma unroll
                    for (int i = 0; i < 2; i++) {
                        int dlo = ntab[i] * 16 + la;
                        float x1 = acc[mt][i][r], x2 = acc[mt][i + 2][r];
                        float cs = a.cosT[pos * 64 + dlo], sn = a.sinT[pos * 64 + dlo];
                        a.K_all[base + dlo]      = f2b(x1 * cs - x2 * sn);
                        a.K_all[base + dlo + 64] = f2b(x2 * cs + x1 * sn);
                    }
                } else {
                    size_t vt = ((size_t)(b * NKV + head) * HD) * STOT + SCACHE + SQV + s;
#pragma unroll
                    for (int i = 0; i < 4; i++) {
                        int d = ntab[i] * 16 + la;
                        a.VT_all[vt + (size_t)d * STOT] = f2b(acc[mt][i][r]);
                    }
                }
            }
        }
    }
}

// qkv work unit: bid in [0,608), r3 mapping.
__device__ __forceinline__ void qkv_work(const MegaArgs& a, u16* smem, int bid) {
    if (bid < 512) {
        int m0 = (bid & 63) * 64;
        int yy = bid >> 6;
        int path = (yy < 4) ? 0 : 1;
        int head = yy & 3;
        qkv_tile(a, smem, a.hv16, (path == 0) ? a.o0 : a.o1, m0, head * 128, path, head);
    } else {
        int g = bid - 512;
        int m0 = (g & 3) * 64;
        int ny = g >> 2;
        int path, head, n0; const u16* Bt;
        if (ny < 16)      { path = 2; head = ny;      Bt = a.o4; n0 = ny * 128; }
        else if (ny < 20) { path = 3; head = ny - 16; Bt = a.o2; n0 = (ny - 16) * 128; }
        else              { path = 4; head = ny - 20; Bt = a.o3; n0 = (ny - 20) * 128; }
        qkv_tile(a, smem, a.ha16, Bt, m0, n0, path, head);
    }
}

// ---------------- attention work unit (bid in [0,448)): single-buffer K/Vt -----------
// LDS: Ks 8192 u16 + Vt 8192 u16 + Ps 4608 u16 = 41984 B (fits the 48 KiB mega budget).
__device__ __forceinline__ void attn_work(const MegaArgs& a, u16* LDS, int bid) {
    int h = bid & 15, b = (bid >> 4) & 3, p = bid >> 6;
    int bh = b * NH + h;
    int kvh = h >> 2;
    const u16* Kb  = a.K_all  + (size_t)(b * NKV + kvh) * STOT * HD;   // [key][d]
    const u16* VTb = a.VT_all + (size_t)(b * NKV + kvh) * HD * STOT;   // [d][key]
    const u16* Qb  = a.Qbuf + (size_t)bh * SQA * HD;
    int tid = threadIdx.x, w = tid >> 6, lane = tid & 63;
    int la = lane & 15, lg = lane >> 4;
    u16* Ks = LDS;              // 64*128
    u16* Vt = LDS + 8192;       // 128*64
    u16* Ps = LDS + 16384;      // 4*1152

    int kr = tid >> 4;
    int ksw = (((tid & 15) * 16) ^ ((kr & 7) << 4)) >> 1;
    int vr = tid >> 3;
    int vsw = (((tid & 7) * 16) ^ ((vr & 7) << 4)) >> 1;

#define ASTG(G) do {                                                                  \
        _Pragma("unroll")                                                             \
        for (int hh = 0; hh < 4; hh++)                                                \
            gload16(Kb + (size_t)((G) * 64 + kr + hh * 16) * HD + ksw,                \
                    &Ks[hh * 2048 + tid * 8]);                                        \
        _Pragma("unroll")                                                             \
        for (int hh = 0; hh < 4; hh++)                                                \
            gload16(VTb + (size_t)(vr + hh * 32) * STOT + (G) * 64 + vsw,             \
                    &Vt[hh * 2048 + tid * 8]);                                        \
    } while (0)

    ASTG(p * 3);
    short8 qf[4];
#pragma unroll
    for (int kk = 0; kk < 4; kk++)
        qf[kk] = *(const short8*)(Qb + (size_t)(w * 16 + la) * HD + kk * 32 + lg * 8);
    f32x4 o_acc[8];
#pragma unroll
    for (int nt = 0; nt < 8; nt++) o_acc[nt] = (f32x4){0.f, 0.f, 0.f, 0.f};
    float m_run[4], l_run[4];
#pragma unroll
    for (int r = 0; r < 4; r++) { m_run[r] = -3e38f; l_run[r] = 0.f; }

    int swr = (la & 7) << 3;
    const float scl = 0.08838834764831845f;  // 1/sqrt(128)
    for (int c = 0; c < 3; c++) {
        int g = p * 3 + c;
        u16 mreg[4][4];
#pragma unroll
        for (int nt = 0; nt < 4; nt++)
#pragma unroll
            for (int r = 0; r < 4; r++)
                mreg[nt][r] = a.maskS[((size_t)(b * SQA + w * 16 + lg * 4 + r)) * STOT +
                                      g * 64 + nt * 16 + la];
        asm volatile("s_waitcnt vmcnt(0)" ::: "memory");
        __builtin_amdgcn_s_barrier();
        asm volatile("" ::: "memory");
        // ---- QK^T ----
        f32x4 s_acc[4];
#pragma unroll
        for (int nt = 0; nt < 4; nt++) s_acc[nt] = (f32x4){0.f, 0.f, 0.f, 0.f};
        __builtin_amdgcn_s_setprio(1);
#pragma unroll
        for (int kk = 0; kk < 4; kk++) {
            int cc = (kk * 32 + lg * 8) ^ swr;
#pragma unroll
            for (int nt = 0; nt < 4; nt++) {
                short8 kf = *(const short8*)&Ks[(nt * 16 + la) * 128 + cc];
                s_acc[nt] = __builtin_amdgcn_mfma_f32_16x16x32_bf16(qf[kk], kf, s_acc[nt], 0, 0, 0);
            }
        }
        __builtin_amdgcn_s_setprio(0);
        // ---- scores: scale, softclamp, mask ----
        float sc[4][4];
#pragma unroll
        for (int nt = 0; nt < 4; nt++) {
#pragma unroll
            for (int r = 0; r < 4; r++) {
                float sv = s_acc[nt][r] * scl;
                float x = sv * 0.02f;
                float t = __expf(-2.0f * fabsf(x));
                float th = __fdividef(1.0f - t, 1.0f + t);
                sv = copysignf(th, x) * 50.0f;
                sv += b2f(mreg[nt][r]);
                sc[nt][r] = sv;
            }
        }
        // ---- online softmax with defer-max ----
#pragma unroll
        for (int r = 0; r < 4; r++) {
            float mx = fmaxf(fmaxf(sc[0][r], sc[1][r]), fmaxf(sc[2][r], sc[3][r]));
#pragma unroll
            for (int sh = 1; sh < 16; sh <<= 1) mx = fmaxf(mx, __shfl_xor(mx, sh, 64));
            if (mx > m_run[r] + 8.0f) {
                float alpha = __expf(m_run[r] - mx);
                m_run[r] = mx;
                l_run[r] *= alpha;
#pragma unroll
                for (int nt = 0; nt < 8; nt++) o_acc[nt][r] *= alpha;
            }
            float rowsum = 0.f;
#pragma unroll
            for (int nt = 0; nt < 4; nt++) {
                float pv = __expf(sc[nt][r] - m_run[r]);
                Ps[w * 1152 + (lg * 4 + r) * 72 + nt * 16 + la] = f2b(pv);
                rowsum += pv;
            }
#pragma unroll
            for (int sh = 1; sh < 16; sh <<= 1) rowsum += __shfl_xor(rowsum, sh, 64);
            l_run[r] += rowsum;
        }
        // ---- PV ----
        __builtin_amdgcn_s_setprio(1);
#pragma unroll
        for (int kk = 0; kk < 2; kk++) {
            short8 pf = *(const short8*)&Ps[w * 1152 + la * 72 + kk * 32 + lg * 8];
            int cc = (kk * 32 + lg * 8) ^ swr;
#pragma unroll
            for (int nt = 0; nt < 8; nt++) {
                short8 vf = *(const short8*)&Vt[(nt * 16 + la) * 64 + cc];
                o_acc[nt] = __builtin_amdgcn_mfma_f32_16x16x32_bf16(pf, vf, o_acc[nt], 0, 0, 0);
            }
        }
        __builtin_amdgcn_s_setprio(0);
        __builtin_amdgcn_s_barrier();        // all waves done reading Ks/Vt
        if (c < 2) ASTG(g + 1);              // safe to overwrite now
    }
#undef ASTG
#pragma unroll
    for (int nt = 0; nt < 8; nt++) {
#pragma unroll
        for (int r = 0; r < 4; r++) {
            int sq = w * 16 + lg * 4 + r;
            a.po[(((size_t)p * 64 + bh) * 64 + sq) * 128 + nt * 16 + la] = f2b(o_acc[nt][r]);
        }
    }
    if (la == 0) {
#pragma unroll
        for (int r = 0; r < 4; r++) {
            int sq = w * 16 + lg * 4 + r;
            size_t mlb = (((size_t)p * 64 + bh) * 64 + sq) * 2;
            a.pml[mlb] = m_run[r];
            a.pml[mlb + 1] = l_run[r];
        }
    }
}

// ---------------- attention reduce work unit (bid in [0,256)) -------------------------
__device__ __forceinline__ void red_work(const MegaArgs& a, float* wgt, int bid) {
    int h = bid & 15, b = (bid >> 4) & 3, qz = (bid >> 6) * 16;
    int bh = b * NH + h;
    int tid = threadIdx.x;
    if (tid < 16) {
        int q = qz + tid;
        float m[NSPLIT], l[NSPLIT], M = -3e38f;
#pragma unroll
        for (int p = 0; p < NSPLIT; p++) {
            size_t mlb = (((size_t)p * 64 + bh) * 64 + q) * 2;
            m[p] = a.pml[mlb]; l[p] = a.pml[mlb + 1];
            M = fmaxf(M, m[p]);
        }
        float L = 0.f;
#pragma unroll
        for (int p = 0; p < NSPLIT; p++) L += l[p] * __expf(m[p] - M);
        float inv = 1.0f / L;
#pragma unroll
        for (int p = 0; p < NSPLIT; p++) wgt[p * 16 + tid] = __expf(m[p] - M) * inv;
    }
    __syncthreads();
    for (int e = tid; e < 16 * 128; e += 256) {
        int q = qz + (e >> 7), d = e & 127;
        float s = 0.f;
#pragma unroll
        for (int p = 0; p < NSPLIT; p++)
            s += b2f(a.po[(((size_t)p * 64 + bh) * 64 + q) * 128 + d]) * wgt[p * 16 + (e >> 7)];
        a.AO[((size_t)(b * SQA + q)) * 2048 + h * HD + d] = f2b(s);
    }
}

// ---------------- output GEMM work unit (bid in [0,256)): 32x64 tiles -----------------
__device__ __forceinline__ void out_work(const MegaArgs& a, u16* smem, int bid) {
    int m0 = (bid & 7) * 32, n0 = (bid >> 3) * 64;
    int tid = threadIdx.x;
    int w = tid >> 6, lane = tid & 63;
    int la = lane & 15, lg = lane >> 4;
    int wm = (w & 1) * 16, wn = (w >> 1) * 32;
    f32x4 acc[2];
#pragma unroll
    for (int j = 0; j < 2; j++) acc[j] = (f32x4){0.f, 0.f, 0.f, 0.f};

    int srow = tid >> 3;
    int scsrc = (((tid & 7) * 16) ^ ((srow & 7) << 4)) >> 1;

#define STAGE_OUT(CB, KB) do {                                                        \
        u16* Ab_ = smem + (CB) * 6144;                                                \
        u16* Bb_ = Ab_ + 2048;                                                        \
        gload16(a.AO + (size_t)(m0 + srow) * DMODEL + (KB) + scsrc, Ab_ + tid * 8);   \
        _Pragma("unroll")                                                             \
        for (int h = 0; h < 2; h++)                                                   \
            gload16(a.o5 + (size_t)(n0 + srow + h * 32) * DMODEL + (KB) + scsrc,      \
                    Bb_ + h * 2048 + tid * 8);                                        \
    } while (0)

    STAGE_OUT(0, 0);
    int cur = 0;
    int swr = (la & 7) << 3;
    for (int kb = 0; kb < DMODEL; kb += 64) {
        if (kb + 64 < DMODEL) {
            STAGE_OUT(cur ^ 1, kb + 64);
            asm volatile("s_waitcnt vmcnt(3)" ::: "memory");
        } else {
            asm volatile("s_waitcnt vmcnt(0)" ::: "memory");
        }
        __builtin_amdgcn_s_barrier();
        asm volatile("" ::: "memory");
        const u16* Ac = smem + cur * 6144;
        const u16* Bc = Ac + 2048;
#pragma unroll
        for (int kk = 0; kk < 2; kk++) {
            int cc = (kk * 32 + lg * 8) ^ swr;
            short8 af = *(const short8*)&Ac[(wm + la) * 64 + cc];
            short8 bf[2];
#pragma unroll
            for (int nt = 0; nt < 2; nt++) bf[nt] = *(const short8*)&Bc[(wn + nt * 16 + la) * 64 + cc];
#pragma unroll
            for (int nt = 0; nt < 2; nt++)
                acc[nt] = __builtin_amdgcn_mfma_f32_16x16x32_bf16(af, bf[nt], acc[nt], 0, 0, 0);
        }
        __builtin_amdgcn_s_barrier();
        cur ^= 1;
    }
#undef STAGE_OUT

#pragma unroll
    for (int r = 0; r < 4; r++) {
        int gm = m0 + wm + lg * 4 + r;
#pragma unroll
        for (int nt = 0; nt < 2; nt++)
            a.out[(size_t)gm * DMODEL + n0 + wn + nt * 16 + la] = acc[nt][r];
    }
}

// ======================= MEGA KERNEL (cooperative, 512 x 256) =========================
// SMEM capped at 49152 B (the 64 KiB cooperative-occupancy limit killed round 6's
// 74752 B version).  49152 B -> 3 blocks/CU occupancy >= the 2/CU needed for 512
// co-resident blocks.  Phases: prep -> qkv -> attn -> red -> out with grid.sync().
__global__ __launch_bounds__(256, 2) void k_mega(MegaArgs a) {
    __shared__ __align__(16) u16 SMEM[24576];    // 49152 B
    cg::grid_group grid = cg::this_grid();
    int b0 = blockIdx.x;       // 0..511

    for (int gx = b0; gx < 9488; gx += 512) {
        __syncthreads();       // protect LDS reuse across virtual iterations
        prep_work(a, SMEM, gx);
    }
    grid.sync();

    qkv_work(a, SMEM, b0);
    if (b0 % 5 == 2 && b0 / 5 < 96) {            // 96 act extras, <=1 per CU
        __syncthreads();                         // prior tile's last LDS reads done
        qkv_work(a, SMEM, 512 + b0 / 5);
    }
    grid.sync();

    if (b0 < 448) attn_work(a, SMEM, b0);
    grid.sync();

    if (b0 < 256) red_work(a, (float*)SMEM, b0);
    grid.sync();

    if (b0 < 256) out_work(a, SMEM, b0);
}

// ======================= fallback wrappers (identical math, 5 launches) ===============
__global__ __launch_bounds__(256) void k_prep_f(MegaArgs a) {
    __shared__ __align__(16) u16 L[4224];
    prep_work(a, L, blockIdx.x);
}
__global__ __launch_bounds__(256) void k_qkv_f(MegaArgs a) {
    __shared__ __align__(16) u16 L[24576];
    qkv_work(a, L, blockIdx.x);
}
__global__ __launch_bounds__(256) void k_attn_f(MegaArgs a) {
    __shared__ __align__(16) u16 L[20992];
    attn_work(a, L, blockIdx.x);
}
__global__ __launch_bounds__(256) void k_red_f(MegaArgs a) {
    __shared__ float W[NSPLIT * 16];
    red_work(a, W, blockIdx.x);
}
__global__ __launch_bounds__(256) void k_out_f(MegaArgs a) {
    __shared__ __align__(16) u16 L[12288];
    out_work(a, L, blockIdx.x);
}

extern "C" void kernel_launch(void* const* d_in, const int* in_sizes, int n_in,
                              void* d_out, int out_size, void* d_ws, size_t ws_size,
                              hipStream_t stream) {
    (void)in_sizes; (void)n_in; (void)out_size;
    const size_t NEED = 65273856;
    if (ws_size < NEED) return;
    char* ws = (char*)d_ws;

    MegaArgs a;
    a.mask    = (const float*)d_in[0];
    a.pos_vlm = (const int*)d_in[1];
    a.pos_act = (const int*)d_in[2];
    a.hv      = (const float*)d_in[3];
    a.ha      = (const float*)d_in[4];
    a.kc      = (const float*)d_in[5];
    a.vc      = (const float*)d_in[6];
    // d_in[7] = Wq_vlm -- unused (only action-query outputs are returned)
    a.w0 = (const float*)d_in[8];    // Wk_vlm
    a.w1 = (const float*)d_in[9];    // Wv_vlm
    a.w2 = (const float*)d_in[11];   // Wk_act
    a.w3 = (const float*)d_in[12];   // Wv_act
    a.w4 = (const float*)d_in[10];   // Wq_act
    a.w5 = (const float*)d_in[13];   // Wo_act

    a.cosT  = (float*)(ws + 0);          // 344064
    a.sinT  = (float*)(ws + 344064);     // 344064
    a.K_all = (u16*)(ws + 688128);       // 5505024
    a.VT_all= (u16*)(ws + 6193152);      // 5505024  [16][128][1344] (d-major)
    a.Qbuf  = (u16*)(ws + 11698176);     // 1048576
    a.AO    = (u16*)(ws + 12746752);     // 1048576
    a.o0    = (u16*)(ws + 13795328);     // WkvT 2097152
    a.o1    = (u16*)(ws + 15892480);     // WvvT 2097152
    a.o4    = (u16*)(ws + 17989632);     // WqaT 8388608
    a.o2    = (u16*)(ws + 26378240);     // WkaT 2097152
    a.o3    = (u16*)(ws + 28475392);     // WvaT 2097152
    a.o5    = (u16*)(ws + 30572544);     // WoT  8388608
    a.po    = (u16*)(ws + 38961152);     // 7340032  (7 splits)
    a.pml   = (float*)(ws + 46301184);   // 458752
    a.maskS = (u16*)(ws + 46759936);     // 688128
    a.hv16  = (u16*)(ws + 47448064);     // 16777216
    a.ha16  = (u16*)(ws + 64225280);     // 1048576  -> end 65273856
    a.out   = (float*)d_out;

    void* params[] = { &a };
    hipError_t err = hipLaunchCooperativeKernel(k_mega, dim3(512), dim3(256),
                                                params, 0, stream);
    if (err != hipSuccess) {
        (void)hipGetLastError();   // clear sticky error, then proven 5-launch path
        hipLaunchKernelGGL(k_prep_f, dim3(9488), dim3(256), 0, stream, a);
        hipLaunchKernelGGL(k_qkv_f,  dim3(608),  dim3(256), 0, stream, a);
        hipLaunchKernelGGL(k_attn_f, dim3(448),  dim3(256), 0, stream, a);
        hipLaunchKernelGGL(k_red_f,  dim3(256),  dim3(256), 0, stream, a);
        hipLaunchKernelGGL(k_out_f,  dim3(256),  dim3(256), 0, stream, a);
    }
}